// Round 1
// baseline (57.759 us; speedup 1.0000x reference)
//
#include <hip/hip_runtime.h>

#define NG 64
#define NT 8192
#define NE 64
#define Z_COEF 0.001f
#define A_COEF 0.001f

#define BLK 256
#define TPB 256          // tokens per block
#define ITERS 8          // per wave: 8 iters * 8 tokens = 64 tokens; 4 waves -> 256 tokens

// ws layout: float probsum[NG*NE] | uint cnt[NG*NE] | float zsum[NG]

__global__ __launch_bounds__(BLK) void router_main(
    const float* __restrict__ logits,
    float* __restrict__ probsum,
    unsigned int* __restrict__ cnt,
    float* __restrict__ zsum)
{
    const int tid  = threadIdx.x;
    const int lane = tid & 63;
    const int wv   = tid >> 6;      // wave in block (0..3)
    const int c    = lane & 7;      // expert chunk: experts c*8 .. c*8+7
    const int tk   = lane >> 3;     // token slot within the wave's 8

    const int g     = blockIdx.x >> 5;                    // 32 blocks per group
    const int tbase = (blockIdx.x & 31) * TPB + wv * (8 * ITERS);

    const float* gbase = logits + (size_t)g * NT * NE;

    __shared__ float        s_ps[NE];
    __shared__ unsigned int s_cnt[NE];
    __shared__ float        s_z;
    if (tid < NE) { s_ps[tid] = 0.f; s_cnt[tid] = 0u; }
    if (tid == 0) s_z = 0.f;
    __syncthreads();

    float accp[8] = {0.f,0.f,0.f,0.f,0.f,0.f,0.f,0.f};
    float accz = 0.f;

    for (int it = 0; it < ITERS; ++it) {
        const int t = tbase + it * 8 + tk;
        const float* row = gbase + (size_t)t * NE + (c << 3);
        const float4 va = *reinterpret_cast<const float4*>(row);
        const float4 vb = *reinterpret_cast<const float4*>(row + 4);
        float v[8] = {va.x, va.y, va.z, va.w, vb.x, vb.y, vb.z, vb.w};

        // local max + argmax (strict > keeps first index on ties)
        float m  = v[0];
        int   mi = 0;
#pragma unroll
        for (int j = 1; j < 8; ++j) {
            if (v[j] > m) { m = v[j]; mi = j; }
        }
        int me = (c << 3) + mi;

        // butterfly across the 8 lanes of this token (xor 1,2,4 stays in-group)
#pragma unroll
        for (int off = 1; off <= 4; off <<= 1) {
            const float om = __shfl_xor(m, off);
            const int   oe = __shfl_xor(me, off);
            if (om > m || (om == m && oe < me)) { m = om; me = oe; }
        }

        // exp + sum
        float e[8];
        float s = 0.f;
#pragma unroll
        for (int j = 0; j < 8; ++j) { e[j] = __expf(v[j] - m); s += e[j]; }
#pragma unroll
        for (int off = 1; off <= 4; off <<= 1) s += __shfl_xor(s, off);

        const float inv = __builtin_amdgcn_rcpf(s);
#pragma unroll
        for (int j = 0; j < 8; ++j) accp[j] += e[j] * inv;

        if (c == 0) {
            const float lz = m + __logf(s);
            accz += lz * lz;
            atomicAdd(&s_cnt[me], 1u);
        }
    }

    // block-level reduce in LDS
#pragma unroll
    for (int j = 0; j < 8; ++j) atomicAdd(&s_ps[(c << 3) + j], accp[j]);
    if (c == 0) atomicAdd(&s_z, accz);
    __syncthreads();

    if (tid < NE) {
        atomicAdd(&probsum[g * NE + tid], s_ps[tid]);
        atomicAdd(&cnt[g * NE + tid], s_cnt[tid]);
    }
    if (tid == 0) atomicAdd(&zsum[g], s_z);
}

__global__ __launch_bounds__(1024) void router_final(
    const float* __restrict__ probsum,
    const unsigned int* __restrict__ cnt,
    const float* __restrict__ zsum,
    const int* __restrict__ capp,
    float* __restrict__ out)
{
    const int tid  = threadIdx.x;
    const int lane = tid & 63;
    const int w    = tid >> 6;  // 0..15
    const unsigned int C = (unsigned int)(*capp);

    __shared__ float s_aux[16];
    __shared__ float s_zz;

    float acc = 0.f;
    for (int g = w; g < NG; g += 16) {
        const unsigned int n = cnt[g * NE + lane];
        const float        P = probsum[g * NE + lane];

        float ovf = (n > C) ? (float)(n - C) : 0.f;
#pragma unroll
        for (int off = 1; off <= 32; off <<= 1) ovf += __shfl_xor(ovf, off);

        float ce = fminf((float)n, (float)C);
        if (lane == 0) ce += ovf;   // dropped tokens all land on expert 0
        acc += ce * P;
    }
#pragma unroll
    for (int off = 1; off <= 32; off <<= 1) acc += __shfl_xor(acc, off);
    if (lane == 0) s_aux[w] = acc;

    if (w == 0) {
        float zz = zsum[lane];
#pragma unroll
        for (int off = 1; off <= 32; off <<= 1) zz += __shfl_xor(zz, off);
        if (lane == 0) s_zz = zz;
    }
    __syncthreads();

    if (tid == 0) {
        float A = 0.f;
#pragma unroll
        for (int i = 0; i < 16; ++i) A += s_aux[i];
        // aux = sum(c_e * P_e) * NE / (NG * NT * NT)
        const float aux_loss = A * ((float)NE / ((float)NG * (float)NT * (float)NT));
        const float z_loss   = s_zz / ((float)NG * (float)NT);
        out[0] = Z_COEF * z_loss + A_COEF * aux_loss;
    }
}

extern "C" void kernel_launch(void* const* d_in, const int* in_sizes, int n_in,
                              void* d_out, int out_size, void* d_ws, size_t ws_size,
                              hipStream_t stream)
{
    const float* logits = (const float*)d_in[0];
    // d_in[1] = attention_mask (unused by the reference forward)
    const int* cap = (const int*)d_in[2];

    float*        probsum = (float*)d_ws;
    unsigned int* cntp    = (unsigned int*)((char*)d_ws + (size_t)NG * NE * sizeof(float));
    float*        zsum    = (float*)((char*)d_ws + 2ull * NG * NE * sizeof(float));

    hipMemsetAsync(d_ws, 0, 2ull * NG * NE * 4 + NG * 4, stream);

    router_main<<<NG * (NT / TPB), BLK, 0, stream>>>(logits, probsum, cntp, zsum);
    router_final<<<1, 1024, 0, stream>>>(probsum, cntp, zsum, cap, (float*)d_out);
}